// Round 1
// baseline (976.936 us; speedup 1.0000x reference)
//
#include <hip/hip_runtime.h>

// masksampling v2: outputs depend ONLY on initmask (x unused).
//   initmask: (32, 1, 512, 512) int32 (0..3)
//   out: mask1, mask2 each (32,3,1024,1024) f32, concatenated.
//
// full-res (r,col) value = PATTERNS[m][r&1][col&1], m = initmask[b, r>>1, col>>1]
// Equality LUTs, bit index = m*4 + (r&1)*2 + (col&1):
//   EQ1 (val==1) = 0x4821, EQ2 (val==2) = 0x1482
//
// v2 structure: ONE thread per mask int2 (2 cells = full-res cols 4j..4j+3).
// Each 8B mask load feeds 12 float4 stores (rows 2rm,2rm+1  x 3 channels x 2
// streams = 192 B written per 8 B read). vs v1: 6x fewer threads, 6x less
// read amplification, one dependent-load stall per 12 KB of wave writes
// instead of per 2 KB.

#define N_F4_PER_OUT 25165824u   // 32*3*1024*1024/4
#define N_MASK_INT2  4194304u    // 32*512*512/2

__global__ __launch_bounds__(256) void masksampling_kernel(const int* __restrict__ im,
                                                           float* __restrict__ out) {
    const unsigned t = blockIdx.x * 256u + threadIdx.x;   // 0 .. 4,194,303
    // t IS the linear int2 index: (b*512 + rm)*256 + j  (131072 = 2^17 int2 per batch)
    const unsigned j  = t & 255u;          // col group (full-res cols 4j..4j+3)
    const unsigned rm = (t >> 8) & 511u;   // mask row (full-res rows 2rm, 2rm+1)
    const unsigned b  = t >> 17;           // batch 0..31

    const int2 m2 = ((const int2*)im)[t];

    const unsigned s0 = (unsigned)m2.x * 4u;   // cols 4j, 4j+1
    const unsigned s1 = (unsigned)m2.y * 4u;   // cols 4j+2, 4j+3

    const unsigned EQ1 = 0x4821u, EQ2 = 0x1482u;
    // row parity p contributes bit offset 2p; col parity q contributes +q
    const float4 f1r0 = make_float4((float)((EQ1 >> s0) & 1u),
                                    (float)((EQ1 >> (s0 + 1u)) & 1u),
                                    (float)((EQ1 >> s1) & 1u),
                                    (float)((EQ1 >> (s1 + 1u)) & 1u));
    const float4 f1r1 = make_float4((float)((EQ1 >> (s0 + 2u)) & 1u),
                                    (float)((EQ1 >> (s0 + 3u)) & 1u),
                                    (float)((EQ1 >> (s1 + 2u)) & 1u),
                                    (float)((EQ1 >> (s1 + 3u)) & 1u));
    const float4 f2r0 = make_float4((float)((EQ2 >> s0) & 1u),
                                    (float)((EQ2 >> (s0 + 1u)) & 1u),
                                    (float)((EQ2 >> s1) & 1u),
                                    (float)((EQ2 >> (s1 + 1u)) & 1u));
    const float4 f2r1 = make_float4((float)((EQ2 >> (s0 + 2u)) & 1u),
                                    (float)((EQ2 >> (s0 + 3u)) & 1u),
                                    (float)((EQ2 >> (s1 + 2u)) & 1u),
                                    (float)((EQ2 >> (s1 + 3u)) & 1u));

    // float4 row index within an output: ((b*3 + c)*1024 + r)*256 + j
    float4* o1 = (float4*)out;
    float4* o2 = o1 + N_F4_PER_OUT;
    unsigned idx = (b * 3072u + 2u * rm) * 256u + j;   // c=0, row 2rm
    #pragma unroll
    for (int c = 0; c < 3; ++c) {
        o1[idx]         = f1r0;   // row 2rm,   stream 1
        o1[idx + 256u]  = f1r1;   // row 2rm+1, stream 1
        o2[idx]         = f2r0;   // row 2rm,   stream 2
        o2[idx + 256u]  = f2r1;   // row 2rm+1, stream 2
        idx += 262144u;           // next channel (1024 rows * 256 float4)
    }
}

extern "C" void kernel_launch(void* const* d_in, const int* in_sizes, int n_in,
                              void* d_out, int out_size, void* d_ws, size_t ws_size,
                              hipStream_t stream) {
    const int* im = (const int*)d_in[1];   // d_in[0] = x (unused)
    float* out = (float*)d_out;
    masksampling_kernel<<<N_MASK_INT2 / 256, 256, 0, stream>>>(im, out);
}

// Round 2
// 962.647 us; speedup vs baseline: 1.0148x; 1.0148x over previous
//
#include <hip/hip_runtime.h>

// masksampling v3: persistent-strip streaming kernel.
//   initmask: (32, 1, 512, 512) int32 (0..3);  out: mask1,mask2 (32,3,1024,1024) f32 concat.
// full-res (r,col) = PATTERNS[m][r&1][col&1], m = initmask[b, r>>1, col>>1]
// Equality LUTs, bit index = m*4 + (r&1)*2 + (col&1): EQ1=0x4821, EQ2=0x1482.
//
// Structure (fill-like): 2048 blocks x 256 thr = 8192 waves = exactly one full
// machine residency; zero wave churn. Each block owns 8 consecutive mask rows
// of one batch. All 8 mask int2 loads are issued up-front (one L3 latency
// bubble per 96 KB of per-wave stores), then 96 fully-unrolled float4 stores
// stream 6 contiguous regions (3 ch x 2 streams), rows advancing linearly.

#define N_F4_PER_OUT 25165824u   // 32*3*1024*1024/4
#define CH_STRIDE    262144u     // 1024*256 float4 per channel

__global__ __launch_bounds__(256) void masksampling_kernel(const int* __restrict__ im,
                                                           float* __restrict__ out) {
    const unsigned blk = blockIdx.x;           // 0..2047
    const unsigned j   = threadIdx.x;          // 0..255 col group (cols 4j..4j+3)
    const unsigned b   = blk >> 6;             // batch 0..31 (64 blocks/batch)
    const unsigned rs  = (blk & 63u) * 8u;     // first mask row of this strip

    const int2* __restrict__ imv = (const int2*)im + (b * 512u + rs) * 256u + j;
    float4* o1 = (float4*)out + (b * 3072u + 2u * rs) * 256u + j;
    float4* o2 = o1 + N_F4_PER_OUT;

    // Batch all mask loads: 8 independent loads in flight, single wait.
    int2 m[8];
    #pragma unroll
    for (int i = 0; i < 8; ++i) m[i] = imv[(unsigned)i * 256u];

    const unsigned EQ1 = 0x4821u, EQ2 = 0x1482u;

    #pragma unroll
    for (int i = 0; i < 8; ++i) {
        const unsigned s0 = (unsigned)m[i].x * 4u;   // cols 4j, 4j+1
        const unsigned s1 = (unsigned)m[i].y * 4u;   // cols 4j+2, 4j+3

        const float4 f1r0 = make_float4((float)((EQ1 >> s0) & 1u),
                                        (float)((EQ1 >> (s0 + 1u)) & 1u),
                                        (float)((EQ1 >> s1) & 1u),
                                        (float)((EQ1 >> (s1 + 1u)) & 1u));
        const float4 f1r1 = make_float4((float)((EQ1 >> (s0 + 2u)) & 1u),
                                        (float)((EQ1 >> (s0 + 3u)) & 1u),
                                        (float)((EQ1 >> (s1 + 2u)) & 1u),
                                        (float)((EQ1 >> (s1 + 3u)) & 1u));
        const float4 f2r0 = make_float4((float)((EQ2 >> s0) & 1u),
                                        (float)((EQ2 >> (s0 + 1u)) & 1u),
                                        (float)((EQ2 >> s1) & 1u),
                                        (float)((EQ2 >> (s1 + 1u)) & 1u));
        const float4 f2r1 = make_float4((float)((EQ2 >> (s0 + 2u)) & 1u),
                                        (float)((EQ2 >> (s0 + 3u)) & 1u),
                                        (float)((EQ2 >> (s1 + 2u)) & 1u),
                                        (float)((EQ2 >> (s1 + 3u)) & 1u));

        float4* p1 = o1 + (unsigned)i * 512u;   // rows 2(rs+i), 2(rs+i)+1
        float4* p2 = o2 + (unsigned)i * 512u;
        p1[0]                   = f1r0;  p1[256u]                  = f1r1;
        p1[CH_STRIDE]           = f1r0;  p1[CH_STRIDE + 256u]      = f1r1;
        p1[2u * CH_STRIDE]      = f1r0;  p1[2u * CH_STRIDE + 256u] = f1r1;
        p2[0]                   = f2r0;  p2[256u]                  = f2r1;
        p2[CH_STRIDE]           = f2r0;  p2[CH_STRIDE + 256u]      = f2r1;
        p2[2u * CH_STRIDE]      = f2r0;  p2[2u * CH_STRIDE + 256u] = f2r1;
    }
}

extern "C" void kernel_launch(void* const* d_in, const int* in_sizes, int n_in,
                              void* d_out, int out_size, void* d_ws, size_t ws_size,
                              hipStream_t stream) {
    const int* im = (const int*)d_in[1];   // d_in[0] = x (unused)
    float* out = (float*)d_out;
    masksampling_kernel<<<2048, 256, 0, stream>>>(im, out);
}